// Round 4
// baseline (160.602 us; speedup 1.0000x reference)
//
#include <hip/hip_runtime.h>
#include <math.h>

#define NMODES 6400
#define TB     256
#define MPT    25                 // modes per thread: TB*MPT == NMODES (one block = all modes)
#define TC     44                 // samples per time-chunk

static __device__ __forceinline__ float softplusf(float x) {
    return log1pf(expf(-fabsf(x))) + fmaxf(x, 0.0f);
}
static __device__ __forceinline__ float sigmoidf(float x) {
    return 1.0f / (1.0f + expf(-x));
}

// ONE kernel: per-thread mode setup (25 modes) -> phasor recurrence over a
// TC-sample chunk -> wave butterfly + LDS cross-wave combine -> plain store.
// Last block to finish (device-scope counter) normalizes the whole output.
__global__ __launch_bounds__(TB, 2) void plate_kernel(
    const float* __restrict__ mu_raw,
    const float* __restrict__ Dmu_raw,
    const float* __restrict__ T0mu_raw,
    const float* __restrict__ Ly_raw,
    const float* __restrict__ xo_raw,
    const float* __restrict__ yo_raw,
    float* __restrict__ out,
    unsigned int* __restrict__ cnt,
    int T)
{
    const int tid = threadIdx.x;
    const int t0  = blockIdx.x * TC;

    const float KF   = 1.0f / 44100.0f;
    const float PI_F = (float)M_PI;
    const double om2sq = (2.0 * M_PI * 500.0) * (2.0 * M_PI * 500.0);
    const float ALPHA_F  = (float)(3.0 * M_LN10 / om2sq * (om2sq / 6.0));
    const float BETA_F   = (float)(3.0 * M_LN10 / om2sq * (1.0 - 1.0 / 6.0));
    const float MAX_OM_F = (float)(10000.0 * 2.0 * M_PI);
    const float MIN_OM_F = (float)(20.0 * 2.0 * M_PI);
    const float KK_F     = (float)((1.0 / 44100.0) * (1.0 / 44100.0));
    const double Kd      = 1.0 / 44100.0;
    const double TWO_PI  = 6.283185307179586476925286766559;
    const double I2PI    = 0.15915494309189533576888376337251;

    // scalar parameter derivation (identical in every thread, broadcast loads)
    float mu   = (softplusf(mu_raw[0])   + 1e-4f) * 2.43f;
    float Dmu  = (softplusf(Dmu_raw[0])  + 1e-4f) * 0.002452f;
    float T0mu = (softplusf(T0mu_raw[0]) + 1e-4f) * 0.004115f;
    float Ly   = 1.1f + 2.9f * sigmoidf(Ly_raw[0]);
    float xo   = 0.245f + 0.255f * sigmoidf(xo_raw[0]);
    float yo   = __fadd_rn(__fmul_rn(0.51f, Ly),
                           __fmul_rn(__fmul_rn(0.49f, Ly), sigmoidf(yo_raw[0])));
    float xi_pi = (float)(0.05 * M_PI);
    float yi    = __fmul_rn(0.1f, Ly);
    float ms    = __fmul_rn(__fmul_rn(__fmul_rn(0.25f, mu), 0.5f), Ly);

    __shared__ float sRed[4][TC];
    __shared__ float red[4];
    __shared__ int   sLast;

    float S[MPT], C[MPT], CW[MPT], SW[MPT];
    #pragma unroll
    for (int j = 0; j < MPT; ++j) {
        int m = j * TB + tid;
        float mf = (float)(m / 80 + 1);
        float nf = (float)(m % 80 + 1);

        float am = __fmul_rn(__fmul_rn(mf, PI_F), 2.0f);
        float bn = __fdiv_rn(__fmul_rn(nf, PI_F), Ly);
        float g1 = __fadd_rn(__fmul_rn(am, am), __fmul_rn(bn, bn));
        float omega_sq = __fadd_rn(__fmul_rn(T0mu, g1),
                                   __fmul_rn(__fmul_rn(Dmu, g1), g1));
        float w = sqrtf(fmaxf(omega_sq, 0.0f));
        float valid = (w <= MAX_OM_F && w >= MIN_OM_F) ? 1.0f : 0.0f;

        float InW = __fmul_rn(
            cosf(__fmul_rn(__fmul_rn(xi_pi, mf), 2.0f)),
            cosf(__fdiv_rn(__fmul_rn(__fmul_rn(yi, PI_F), nf), Ly)));
        float OutW = __fmul_rn(
            cosf(__fmul_rn(__fmul_rn(__fmul_rn(xo, PI_F), mf), 2.0f)),
            cosf(__fdiv_rn(__fmul_rn(__fmul_rn(yo, PI_F), nf), Ly)));

        float sigma = __fadd_rn(ALPHA_F, __fmul_rn(BETA_F, __fmul_rn(w, w)));
        float P = __fmul_rn(
            __fdiv_rn(__fmul_rn(__fmul_rn(__fmul_rn(OutW, InW), KK_F),
                                expf(__fmul_rn(-sigma, KF))),
                      ms),
            valid);
        float den = __fadd_rn(sinf(__fmul_rn(w, KF)), 1e-8f);
        float A = __fdiv_rn(P, den);

        // rotation constants (float trig: error ~1e-7, x44 steps -> ~5e-6)
        float ds  = __expf(__fmul_rn(-sigma, KF));
        float sth, cth;
        sincosf(__fmul_rn(w, KF), &sth, &cth);
        CW[j] = __fmul_rn(ds, cth);
        SW[j] = __fmul_rn(ds, sth);

        // exact phase init at t0 (double range reduction), env in float
        double ph = (double)t0 * (double)w * Kd;
        double q  = rint(ph * I2PI);
        float  r  = (float)fma(-q, TWO_PI, ph);
        float s0, c0;
        __sincosf(r, &s0, &c0);
        float env = A * __expf(-sigma * (float)(t0 - 1) * KF);
        S[j] = env * s0;
        C[j] = env * c0;
    }

    const int wv = tid >> 6, lane = tid & 63;

    #pragma unroll 1
    for (int tt = 0; tt < TC; ++tt) {
        // 4-way interleaved tree sum of current S[]
        float a0 = S[0], a1 = S[1], a2 = S[2], a3 = S[3];
        #pragma unroll
        for (int j = 4; j < MPT; j += 4) a0 += S[j];
        #pragma unroll
        for (int j = 5; j < MPT; j += 4) a1 += S[j];
        #pragma unroll
        for (int j = 6; j < MPT; j += 4) a2 += S[j];
        #pragma unroll
        for (int j = 7; j < MPT; j += 4) a3 += S[j];
        float acc = (a0 + a1) + (a2 + a3);
        // rotate states (independent work overlaps the butterfly's shfl latency)
        #pragma unroll
        for (int j = 0; j < MPT; ++j) {
            float nS = __fmaf_rn(S[j], CW[j],  C[j] * SW[j]);
            float nC = __fmaf_rn(C[j], CW[j], -(S[j] * SW[j]));
            S[j] = nS;
            C[j] = nC;
        }
        #pragma unroll
        for (int off = 32; off > 0; off >>= 1)
            acc += __shfl_xor(acc, off, 64);
        if (lane == 0) sRed[wv][tt] = acc;
    }
    __syncthreads();
    for (int tt = tid; tt < TC; tt += TB) {
        int t = t0 + tt;
        if (t < T)
            out[t] = (sRed[0][tt] + sRed[1][tt]) + (sRed[2][tt] + sRed[3][tt]);
    }

    // ---- last-block normalization ----
    __threadfence();                       // release our out[] stores
    __syncthreads();
    if (tid == 0) {
        unsigned int old = atomicAdd(cnt, 1u);
        sLast = (old == gridDim.x - 1) ? 1 : 0;
    }
    __syncthreads();
    if (sLast) {
        __threadfence();                   // acquire all blocks' out[] stores
        float mx = 0.0f;
        for (int i = tid; i < T; i += TB) mx = fmaxf(mx, fabsf(out[i]));
        #pragma unroll
        for (int off = 32; off > 0; off >>= 1)
            mx = fmaxf(mx, __shfl_xor(mx, off, 64));
        if (lane == 0) red[wv] = mx;
        __syncthreads();
        float pk = fmaxf(fmaxf(red[0], red[1]), fmaxf(red[2], red[3])) + 1e-8f;
        for (int i = tid; i < T; i += TB) out[i] = __fdiv_rn(out[i], pk);
    }
}

extern "C" void kernel_launch(void* const* d_in, const int* in_sizes, int n_in,
                              void* d_out, int out_size, void* d_ws, size_t ws_size,
                              hipStream_t stream)
{
    const float* mu   = (const float*)d_in[0];
    const float* Dmu  = (const float*)d_in[1];
    const float* T0mu = (const float*)d_in[2];
    const float* Lyr  = (const float*)d_in[3];
    const float* xor_ = (const float*)d_in[4];
    const float* yor_ = (const float*)d_in[5];
    float* out = (float*)d_out;
    unsigned int* cnt = (unsigned int*)d_ws;

    int T = out_size;
    int tchunks = (T + TC - 1) / TC;

    hipMemsetAsync(cnt, 0, sizeof(unsigned int), stream);   // graph-capturable
    plate_kernel<<<tchunks, TB, 0, stream>>>(mu, Dmu, T0mu, Lyr, xor_, yor_, out, cnt, T);
}

// Round 5
// 147.904 us; speedup vs baseline: 1.0858x; 1.0858x over previous
//
#include <hip/hip_runtime.h>
#include <math.h>

#define NMODES 6400
#define TB     256
#define MPT    25                 // modes per thread: TB*MPT == NMODES (one block = all modes)
#define TC     44                 // samples per time-chunk

static __device__ __forceinline__ float softplusf(float x) {
    return log1pf(expf(-fabsf(x))) + fmaxf(x, 0.0f);
}
static __device__ __forceinline__ float sigmoidf(float x) {
    return 1.0f / (1.0f + expf(-x));
}

// Runs ONCE over 6400 modes: A (amplitude incl. validity), omega, sigma,
// rotation constants cw/sw (double-computed). ~3 us.
__global__ void setup_kernel(const float* __restrict__ mu_raw,
                             const float* __restrict__ Dmu_raw,
                             const float* __restrict__ T0mu_raw,
                             const float* __restrict__ Ly_raw,
                             const float* __restrict__ xo_raw,
                             const float* __restrict__ yo_raw,
                             float* __restrict__ wsA,
                             float* __restrict__ wsW,
                             float* __restrict__ wsS,
                             float* __restrict__ wsCW,
                             float* __restrict__ wsSW)
{
    int id = blockIdx.x * blockDim.x + threadIdx.x;
    if (id >= NMODES) return;

    const float KF   = 1.0f / 44100.0f;
    const float PI_F = (float)M_PI;
    const double om2sq = (2.0 * M_PI * 500.0) * (2.0 * M_PI * 500.0);
    const float ALPHA_F  = (float)(3.0 * M_LN10 / om2sq * (om2sq / 6.0));
    const float BETA_F   = (float)(3.0 * M_LN10 / om2sq * (1.0 - 1.0 / 6.0));
    const float MAX_OM_F = (float)(10000.0 * 2.0 * M_PI);
    const float MIN_OM_F = (float)(20.0 * 2.0 * M_PI);
    const float KK_F     = (float)((1.0 / 44100.0) * (1.0 / 44100.0));

    float mu   = (softplusf(mu_raw[0])   + 1e-4f) * 2.43f;
    float Dmu  = (softplusf(Dmu_raw[0])  + 1e-4f) * 0.002452f;
    float T0mu = (softplusf(T0mu_raw[0]) + 1e-4f) * 0.004115f;
    float Ly   = 1.1f + 2.9f * sigmoidf(Ly_raw[0]);
    float xo   = 0.245f + 0.255f * sigmoidf(xo_raw[0]);
    float yo   = __fadd_rn(__fmul_rn(0.51f, Ly),
                           __fmul_rn(__fmul_rn(0.49f, Ly), sigmoidf(yo_raw[0])));

    float mf = (float)(id / 80 + 1);
    float nf = (float)(id % 80 + 1);

    float am = __fmul_rn(__fmul_rn(mf, PI_F), 2.0f);
    float bn = __fdiv_rn(__fmul_rn(nf, PI_F), Ly);
    float g1 = __fadd_rn(__fmul_rn(am, am), __fmul_rn(bn, bn));
    float omega_sq = __fadd_rn(__fmul_rn(T0mu, g1),
                               __fmul_rn(__fmul_rn(Dmu, g1), g1));
    float omega = sqrtf(fmaxf(omega_sq, 0.0f));
    float valid = (omega <= MAX_OM_F && omega >= MIN_OM_F) ? 1.0f : 0.0f;

    float xi_pi = (float)(0.05 * M_PI);
    float yi = __fmul_rn(0.1f, Ly);
    float InW = __fmul_rn(
        cosf(__fmul_rn(__fmul_rn(xi_pi, mf), 2.0f)),
        cosf(__fdiv_rn(__fmul_rn(__fmul_rn(yi, PI_F), nf), Ly)));
    float OutW = __fmul_rn(
        cosf(__fmul_rn(__fmul_rn(__fmul_rn(xo, PI_F), mf), 2.0f)),
        cosf(__fdiv_rn(__fmul_rn(__fmul_rn(yo, PI_F), nf), Ly)));

    float sigma = __fadd_rn(ALPHA_F, __fmul_rn(BETA_F, __fmul_rn(omega, omega)));
    float ms = __fmul_rn(__fmul_rn(__fmul_rn(0.25f, mu), 0.5f), Ly);
    float P = __fmul_rn(
        __fdiv_rn(__fmul_rn(__fmul_rn(__fmul_rn(OutW, InW), KK_F),
                            expf(__fmul_rn(-sigma, KF))),
                  ms),
        valid);
    float den = __fadd_rn(sinf(__fmul_rn(omega, KF)), 1e-8f);
    float A = __fdiv_rn(P, den);

    const double Kd = 1.0 / 44100.0;
    double th = (double)omega * Kd;
    double dd = exp(-(double)sigma * Kd);
    wsA[id]  = A;
    wsW[id]  = omega;
    wsS[id]  = sigma;
    wsCW[id] = (float)(dd * cos(th));
    wsSW[id] = (float)(dd * sin(th));
}

// One block = ALL 6400 modes for a TC-sample time range (phasor recurrence,
// 5 VALU/mode-step). Per t: tree-sum, 64-lane butterfly, LDS cross-wave
// combine, plain store. Last block (device-scope counter) normalizes output.
__global__ __launch_bounds__(TB, 2) void accum_kernel(
    const float* __restrict__ wsA,
    const float* __restrict__ wsW,
    const float* __restrict__ wsS,
    const float* __restrict__ wsCW,
    const float* __restrict__ wsSW,
    float* __restrict__ out,
    unsigned int* __restrict__ cnt,
    int T)
{
    const int tid = threadIdx.x;
    const int t0  = blockIdx.x * TC;

    const float  KF     = 1.0f / 44100.0f;
    const double Kd     = 1.0 / 44100.0;
    const double TWO_PI = 6.283185307179586476925286766559;
    const double I2PI   = 0.15915494309189533576888376337251;

    __shared__ float sRed[4][TC];
    __shared__ float red[4];
    __shared__ int   sLast;

    float S[MPT], C[MPT], CW[MPT], SW[MPT];
    #pragma unroll
    for (int j = 0; j < MPT; ++j) {
        int m = j * TB + tid;
        float A  = wsA[m];
        float w  = wsW[m];
        float sg = wsS[m];
        CW[j] = wsCW[m];
        SW[j] = wsSW[m];
        // exact phase init at t0 (double range reduction), env in float
        double ph = (double)t0 * (double)w * Kd;
        double q  = rint(ph * I2PI);
        float  r  = (float)fma(-q, TWO_PI, ph);
        float s0, c0;
        __sincosf(r, &s0, &c0);
        float env = A * __expf(-sg * (float)(t0 - 1) * KF);
        S[j] = env * s0;
        C[j] = env * c0;
    }

    const int wv = tid >> 6, lane = tid & 63;

    #pragma unroll 1
    for (int tt = 0; tt < TC; ++tt) {
        // 4-way interleaved tree sum of current S[]
        float a0 = S[0], a1 = S[1], a2 = S[2], a3 = S[3];
        #pragma unroll
        for (int j = 4; j < MPT; j += 4) a0 += S[j];
        #pragma unroll
        for (int j = 5; j < MPT; j += 4) a1 += S[j];
        #pragma unroll
        for (int j = 6; j < MPT; j += 4) a2 += S[j];
        #pragma unroll
        for (int j = 7; j < MPT; j += 4) a3 += S[j];
        float acc = (a0 + a1) + (a2 + a3);
        // rotate states (independent work overlaps the butterfly's shfl latency)
        #pragma unroll
        for (int j = 0; j < MPT; ++j) {
            float nS = __fmaf_rn(S[j], CW[j],  C[j] * SW[j]);
            float nC = __fmaf_rn(C[j], CW[j], -(S[j] * SW[j]));
            S[j] = nS;
            C[j] = nC;
        }
        #pragma unroll
        for (int off = 32; off > 0; off >>= 1)
            acc += __shfl_xor(acc, off, 64);
        if (lane == 0) sRed[wv][tt] = acc;
    }
    __syncthreads();
    for (int tt = tid; tt < TC; tt += TB) {
        int t = t0 + tt;
        if (t < T)
            out[t] = (sRed[0][tt] + sRed[1][tt]) + (sRed[2][tt] + sRed[3][tt]);
    }

    // ---- last-block normalization ----
    __threadfence();                       // release our out[] stores
    __syncthreads();
    if (tid == 0) {
        unsigned int old = atomicAdd(cnt, 1u);
        sLast = (old == gridDim.x - 1) ? 1 : 0;
    }
    __syncthreads();
    if (sLast) {
        __threadfence();                   // acquire all blocks' out[] stores
        float mx = 0.0f;
        for (int i = tid; i < T; i += TB) mx = fmaxf(mx, fabsf(out[i]));
        #pragma unroll
        for (int off = 32; off > 0; off >>= 1)
            mx = fmaxf(mx, __shfl_xor(mx, off, 64));
        if (lane == 0) red[wv] = mx;
        __syncthreads();
        float pk = fmaxf(fmaxf(red[0], red[1]), fmaxf(red[2], red[3])) + 1e-8f;
        for (int i = tid; i < T; i += TB) out[i] = __fdiv_rn(out[i], pk);
    }
}

extern "C" void kernel_launch(void* const* d_in, const int* in_sizes, int n_in,
                              void* d_out, int out_size, void* d_ws, size_t ws_size,
                              hipStream_t stream)
{
    const float* mu   = (const float*)d_in[0];
    const float* Dmu  = (const float*)d_in[1];
    const float* T0mu = (const float*)d_in[2];
    const float* Lyr  = (const float*)d_in[3];
    const float* xor_ = (const float*)d_in[4];
    const float* yor_ = (const float*)d_in[5];
    float* out = (float*)d_out;

    float* ws   = (float*)d_ws;
    float* wsA  = ws;
    float* wsW  = ws + NMODES;
    float* wsS  = ws + 2 * NMODES;
    float* wsCW = ws + 3 * NMODES;
    float* wsSW = ws + 4 * NMODES;
    unsigned int* cnt = (unsigned int*)(ws + 5 * NMODES);

    int T = out_size;
    int tchunks = (T + TC - 1) / TC;

    hipMemsetAsync(cnt, 0, sizeof(unsigned int), stream);   // graph-capturable
    setup_kernel<<<(NMODES + TB - 1) / TB, TB, 0, stream>>>(mu, Dmu, T0mu, Lyr, xor_, yor_,
                                                            wsA, wsW, wsS, wsCW, wsSW);
    accum_kernel<<<tchunks, TB, 0, stream>>>(wsA, wsW, wsS, wsCW, wsSW, out, cnt, T);
}

// Round 6
// 122.579 us; speedup vs baseline: 1.3102x; 1.2066x over previous
//
#include <hip/hip_runtime.h>
#include <math.h>

#define NMODES 6400
#define TB     256
#define MPT    5                  // modes per thread
#define MG     5                  // mode groups: TB*MPT*MG == NMODES
#define BATCH  4                  // samples per butterfly batch
#define TC     84                 // samples per time-chunk (divisible by BATCH)

static __device__ __forceinline__ float softplusf(float x) {
    return log1pf(expf(-fabsf(x))) + fmaxf(x, 0.0f);
}
static __device__ __forceinline__ float sigmoidf(float x) {
    return 1.0f / (1.0f + expf(-x));
}

// Runs ONCE over 6400 modes: A (amplitude incl. validity), omega, sigma,
// rotation constants cw/sw (double-computed). ~3 us.
__global__ void setup_kernel(const float* __restrict__ mu_raw,
                             const float* __restrict__ Dmu_raw,
                             const float* __restrict__ T0mu_raw,
                             const float* __restrict__ Ly_raw,
                             const float* __restrict__ xo_raw,
                             const float* __restrict__ yo_raw,
                             float* __restrict__ wsA,
                             float* __restrict__ wsW,
                             float* __restrict__ wsS,
                             float* __restrict__ wsCW,
                             float* __restrict__ wsSW)
{
    int id = blockIdx.x * blockDim.x + threadIdx.x;
    if (id >= NMODES) return;

    const float KF   = 1.0f / 44100.0f;
    const float PI_F = (float)M_PI;
    const double om2sq = (2.0 * M_PI * 500.0) * (2.0 * M_PI * 500.0);
    const float ALPHA_F  = (float)(3.0 * M_LN10 / om2sq * (om2sq / 6.0));
    const float BETA_F   = (float)(3.0 * M_LN10 / om2sq * (1.0 - 1.0 / 6.0));
    const float MAX_OM_F = (float)(10000.0 * 2.0 * M_PI);
    const float MIN_OM_F = (float)(20.0 * 2.0 * M_PI);
    const float KK_F     = (float)((1.0 / 44100.0) * (1.0 / 44100.0));

    float mu   = (softplusf(mu_raw[0])   + 1e-4f) * 2.43f;
    float Dmu  = (softplusf(Dmu_raw[0])  + 1e-4f) * 0.002452f;
    float T0mu = (softplusf(T0mu_raw[0]) + 1e-4f) * 0.004115f;
    float Ly   = 1.1f + 2.9f * sigmoidf(Ly_raw[0]);
    float xo   = 0.245f + 0.255f * sigmoidf(xo_raw[0]);
    float yo   = __fadd_rn(__fmul_rn(0.51f, Ly),
                           __fmul_rn(__fmul_rn(0.49f, Ly), sigmoidf(yo_raw[0])));

    float mf = (float)(id / 80 + 1);
    float nf = (float)(id % 80 + 1);

    float am = __fmul_rn(__fmul_rn(mf, PI_F), 2.0f);
    float bn = __fdiv_rn(__fmul_rn(nf, PI_F), Ly);
    float g1 = __fadd_rn(__fmul_rn(am, am), __fmul_rn(bn, bn));
    float omega_sq = __fadd_rn(__fmul_rn(T0mu, g1),
                               __fmul_rn(__fmul_rn(Dmu, g1), g1));
    float omega = sqrtf(fmaxf(omega_sq, 0.0f));
    float valid = (omega <= MAX_OM_F && omega >= MIN_OM_F) ? 1.0f : 0.0f;

    float xi_pi = (float)(0.05 * M_PI);
    float yi = __fmul_rn(0.1f, Ly);
    float InW = __fmul_rn(
        cosf(__fmul_rn(__fmul_rn(xi_pi, mf), 2.0f)),
        cosf(__fdiv_rn(__fmul_rn(__fmul_rn(yi, PI_F), nf), Ly)));
    float OutW = __fmul_rn(
        cosf(__fmul_rn(__fmul_rn(__fmul_rn(xo, PI_F), mf), 2.0f)),
        cosf(__fdiv_rn(__fmul_rn(__fmul_rn(yo, PI_F), nf), Ly)));

    float sigma = __fadd_rn(ALPHA_F, __fmul_rn(BETA_F, __fmul_rn(omega, omega)));
    float ms = __fmul_rn(__fmul_rn(__fmul_rn(0.25f, mu), 0.5f), Ly);
    float P = __fmul_rn(
        __fdiv_rn(__fmul_rn(__fmul_rn(__fmul_rn(OutW, InW), KK_F),
                            expf(__fmul_rn(-sigma, KF))),
                  ms),
        valid);
    float den = __fadd_rn(sinf(__fmul_rn(omega, KF)), 1e-8f);
    float A = __fdiv_rn(P, den);

    const double Kd = 1.0 / 44100.0;
    double th = (double)omega * Kd;
    double dd = exp(-(double)sigma * Kd);
    wsA[id]  = A;
    wsW[id]  = omega;
    wsS[id]  = sigma;
    wsCW[id] = (float)(dd * cos(th));
    wsSW[id] = (float)(dd * sin(th));
}

// Thread owns 5 modes; per BATCH=4 samples: 4 rotation steps with per-lane
// accumulators, then 4 INDEPENDENT interleaved 64-lane butterflies (their
// shfl latencies overlap), then lane0 fires 4 pipelined atomicAdds.
// Grid 263x5 = 1315 blocks (~5 waves/SIMD) hides the remaining latency.
__global__ __launch_bounds__(TB) void accum_kernel(
    const float* __restrict__ wsA,
    const float* __restrict__ wsW,
    const float* __restrict__ wsS,
    const float* __restrict__ wsCW,
    const float* __restrict__ wsSW,
    float* __restrict__ out, int T)
{
    const int tid  = threadIdx.x;
    const int t0   = blockIdx.x * TC;
    const int base = blockIdx.y * (TB * MPT);

    const float  KF     = 1.0f / 44100.0f;
    const double Kd     = 1.0 / 44100.0;
    const double TWO_PI = 6.283185307179586476925286766559;
    const double I2PI   = 0.15915494309189533576888376337251;

    float S[MPT], C[MPT], CW[MPT], SW[MPT];
    #pragma unroll
    for (int j = 0; j < MPT; ++j) {
        int m = base + j * TB + tid;
        float A  = wsA[m];
        float w  = wsW[m];
        float sg = wsS[m];
        CW[j] = wsCW[m];
        SW[j] = wsSW[m];
        // exact phase init at t0 (double range reduction), env in float
        double ph = (double)t0 * (double)w * Kd;
        double q  = rint(ph * I2PI);
        float  r  = (float)fma(-q, TWO_PI, ph);
        float s0, c0;
        __sincosf(r, &s0, &c0);
        float env = A * __expf(-sg * (float)(t0 - 1) * KF);
        S[j] = env * s0;
        C[j] = env * c0;
    }

    const int lane = tid & 63;

    #pragma unroll 1
    for (int it = 0; it < TC; it += BATCH) {
        float acc[BATCH];
        #pragma unroll
        for (int b = 0; b < BATCH; ++b) {
            // per-lane sum of current S (sample t0+it+b), short tree
            float a01 = S[0] + S[1];
            float a23 = S[2] + S[3];
            acc[b] = (a01 + a23) + S[4];
            // advance all 5 phasors one step
            #pragma unroll
            for (int j = 0; j < MPT; ++j) {
                float nS = __fmaf_rn(S[j], CW[j],  C[j] * SW[j]);
                float nC = __fmaf_rn(C[j], CW[j], -(S[j] * SW[j]));
                S[j] = nS;
                C[j] = nC;
            }
        }
        // 4 independent butterflies, interleaved so shfl latencies overlap
        #pragma unroll
        for (int off = 32; off > 0; off >>= 1) {
            #pragma unroll
            for (int b = 0; b < BATCH; ++b)
                acc[b] += __shfl_xor(acc[b], off, 64);
        }
        if (lane == 0) {
            int t = t0 + it;
            #pragma unroll
            for (int b = 0; b < BATCH; ++b)
                if (t + b < T) atomicAdd(&out[t + b], acc[b]);
        }
    }
}

// Single block: find peak |out|, then divide through.
__global__ __launch_bounds__(1024) void norm_kernel(float* __restrict__ out, int T)
{
    __shared__ float red[16];
    __shared__ float peakv;
    float mx = 0.0f;
    for (int i = threadIdx.x; i < T; i += 1024) mx = fmaxf(mx, fabsf(out[i]));
    #pragma unroll
    for (int off = 32; off > 0; off >>= 1)
        mx = fmaxf(mx, __shfl_xor(mx, off, 64));
    int lane = threadIdx.x & 63, wv = threadIdx.x >> 6;
    if (lane == 0) red[wv] = mx;
    __syncthreads();
    if (threadIdx.x == 0) {
        float m = red[0];
        #pragma unroll
        for (int i = 1; i < 16; ++i) m = fmaxf(m, red[i]);
        peakv = m + 1e-8f;
    }
    __syncthreads();
    float pk = peakv;
    for (int i = threadIdx.x; i < T; i += 1024) out[i] = __fdiv_rn(out[i], pk);
}

extern "C" void kernel_launch(void* const* d_in, const int* in_sizes, int n_in,
                              void* d_out, int out_size, void* d_ws, size_t ws_size,
                              hipStream_t stream)
{
    const float* mu   = (const float*)d_in[0];
    const float* Dmu  = (const float*)d_in[1];
    const float* T0mu = (const float*)d_in[2];
    const float* Lyr  = (const float*)d_in[3];
    const float* xor_ = (const float*)d_in[4];
    const float* yor_ = (const float*)d_in[5];
    float* out = (float*)d_out;

    float* ws   = (float*)d_ws;
    float* wsA  = ws;
    float* wsW  = ws + NMODES;
    float* wsS  = ws + 2 * NMODES;
    float* wsCW = ws + 3 * NMODES;
    float* wsSW = ws + 4 * NMODES;

    int T = out_size;
    int tchunks = (T + TC - 1) / TC;

    hipMemsetAsync(out, 0, (size_t)T * sizeof(float), stream);  // graph-capturable
    setup_kernel<<<(NMODES + TB - 1) / TB, TB, 0, stream>>>(mu, Dmu, T0mu, Lyr, xor_, yor_,
                                                            wsA, wsW, wsS, wsCW, wsSW);
    accum_kernel<<<dim3(tchunks, MG), TB, 0, stream>>>(wsA, wsW, wsS, wsCW, wsSW, out, T);
    norm_kernel<<<1, 1024, 0, stream>>>(out, T);
}